// Round 5
// baseline (2489.065 us; speedup 1.0000x reference)
//
#include <hip/hip_runtime.h>
#include <math.h>

#define NT 4096
#define DM 1152
#define NH 16
#define DH 72
#define KRET 1638
#define NPR (NT - KRET)
#define CSB 8
#define CHUNK 205
#define SCALE 0.11785113019775793f
#define RSPLIT 2048.0f
#define INV_RSPLIT 4.8828125e-4f

typedef __attribute__((ext_vector_type(8))) short bf16x8;
typedef _Float16 f16;
typedef __attribute__((ext_vector_type(8))) _Float16 f16x8;
typedef __attribute__((ext_vector_type(4))) float f32x4;
typedef unsigned short ushort_t;

#define MFMA16(a, b, c) __builtin_amdgcn_mfma_f32_16x16x32_f16(a, b, c, 0, 0, 0)
#define MFMABF(a, b, c) __builtin_amdgcn_mfma_f32_16x16x32_bf16(a, b, c, 0, 0, 0)

__device__ inline ushort_t f2b(float f) {
    union { float f; unsigned int u; } v; v.f = f;
    unsigned int u = v.u;
    return (ushort_t)((u + 0x7FFFu + ((u >> 16) & 1u)) >> 16);
}

// ---------- split x into fp16 hi/lo(x2048) planes + bf16 copy ----------------
__global__ __launch_bounds__(256) void split_x(
    const float* __restrict__ in, f16* __restrict__ x0, f16* __restrict__ x1,
    ushort_t* __restrict__ xb, int nElem)
{
    int i = blockIdx.x * 256 + threadIdx.x;
    int stride = gridDim.x * 256;
    for (; i < nElem; i += stride) {
        float v = in[i];
        f16 h0 = (f16)v;
        float res = (v - (float)h0) * RSPLIT;
        x0[i] = h0;
        x1[i] = (f16)res;
        xb[i] = f2b(v);
    }
}

__global__ __launch_bounds__(256) void transposeW_split(
    const float* __restrict__ W, f16* __restrict__ T0, f16* __restrict__ T1, int n)
{
    __shared__ float t[32][33];
    int bx = blockIdx.x * 32, by = blockIdx.y * 32;
    int tx = threadIdx.x & 31, ty = threadIdx.x >> 5;
    for (int i = ty; i < 32; i += 8)
        t[i][tx] = W[(size_t)(by + i) * n + bx + tx];
    __syncthreads();
    for (int i = ty; i < 32; i += 8) {
        float v = t[tx][i];
        f16 h0 = (f16)v;
        float res = (v - (float)h0) * RSPLIT;
        T0[(size_t)(bx + i) * n + by + tx] = h0;
        T1[(size_t)(bx + i) * n + by + tx] = (f16)res;
    }
}

__global__ __launch_bounds__(256) void transposeW_bf16(
    const float* __restrict__ W, ushort_t* __restrict__ WT, int n)
{
    __shared__ ushort_t t[32][33];
    int bx = blockIdx.x * 32, by = blockIdx.y * 32;
    int tx = threadIdx.x & 31, ty = threadIdx.x >> 5;
    for (int i = ty; i < 32; i += 8)
        t[i][tx] = f2b(W[(size_t)(by + i) * n + bx + tx]);
    __syncthreads();
    for (int i = ty; i < 32; i += 8)
        WT[(size_t)(bx + i) * n + by + tx] = t[tx][i];
}

__global__ __launch_bounds__(256) void transposeB16(
    const ushort_t* __restrict__ in, ushort_t* __restrict__ out,
    int rows, int cols)
{
    __shared__ ushort_t t[32][33];
    int bx = blockIdx.x * 32, by = blockIdx.y * 32;
    int tx = threadIdx.x & 31, ty = threadIdx.x >> 5;
    for (int i = ty; i < 32; i += 8)
        t[i][tx] = in[(size_t)(by + i) * cols + bx + tx];
    __syncthreads();
    for (int i = ty; i < 32; i += 8)
        out[(size_t)(bx + i) * rows + by + tx] = t[tx][i];
}

// ---------- LDS-tiled fp32-quality projection (3-term split-f16 MFMA) --------
__global__ __launch_bounds__(256) void proj_split2(
    const f16* __restrict__ A0, const f16* __restrict__ A1,
    const f16* __restrict__ B0, const f16* __restrict__ B1,
    f16* __restrict__ Q0, f16* __restrict__ Q1)
{
    __shared__ __align__(16) f16 As0[128][40];
    __shared__ __align__(16) f16 As1[128][40];
    __shared__ __align__(16) f16 Bs0[64][40];
    __shared__ __align__(16) f16 Bs1[64][40];
    const int tid = threadIdx.x;
    const int wave = tid >> 6, lane = tid & 63;
    const int r = lane & 15, g = lane >> 4;
    const int row0 = blockIdx.y * 128;
    const int col0 = blockIdx.x * 64;
    f32x4 accM[2][4] = {}, accC[2][4] = {};
    for (int k0 = 0; k0 < DM; k0 += 32) {
        for (int idx = tid; idx < 128 * 4; idx += 256) {
            int row = idx >> 2, c = idx & 3;
            size_t src = (size_t)(row0 + row) * DM + k0 + c * 8;
            *(f16x8*)&As0[row][c * 8] = *(const f16x8*)(A0 + src);
            *(f16x8*)&As1[row][c * 8] = *(const f16x8*)(A1 + src);
        }
        for (int idx = tid; idx < 64 * 4; idx += 256) {
            int row = idx >> 2, c = idx & 3;
            size_t src = (size_t)(col0 + row) * DM + k0 + c * 8;
            *(f16x8*)&Bs0[row][c * 8] = *(const f16x8*)(B0 + src);
            *(f16x8*)&Bs1[row][c * 8] = *(const f16x8*)(B1 + src);
        }
        __syncthreads();
        f16x8 a0[2], a1[2], b0[4], b1[4];
#pragma unroll
        for (int rf = 0; rf < 2; ++rf) {
            a0[rf] = *(const f16x8*)&As0[wave * 32 + rf * 16 + r][g * 8];
            a1[rf] = *(const f16x8*)&As1[wave * 32 + rf * 16 + r][g * 8];
        }
#pragma unroll
        for (int cf = 0; cf < 4; ++cf) {
            b0[cf] = *(const f16x8*)&Bs0[cf * 16 + r][g * 8];
            b1[cf] = *(const f16x8*)&Bs1[cf * 16 + r][g * 8];
        }
#pragma unroll
        for (int rf = 0; rf < 2; ++rf)
#pragma unroll
            for (int cf = 0; cf < 4; ++cf) {
                accM[rf][cf] = MFMA16(a0[rf], b0[cf], accM[rf][cf]);
                accC[rf][cf] = MFMA16(a0[rf], b1[cf], accC[rf][cf]);
                accC[rf][cf] = MFMA16(a1[rf], b0[cf], accC[rf][cf]);
            }
        __syncthreads();
    }
#pragma unroll
    for (int rf = 0; rf < 2; ++rf)
#pragma unroll
        for (int cf = 0; cf < 4; ++cf) {
            int col = col0 + cf * 16 + r;
#pragma unroll
            for (int j = 0; j < 4; ++j) {
                int row = row0 + wave * 32 + rf * 16 + g * 4 + j;
                float v = accM[rf][cf][j] + accC[rf][cf][j] * INV_RSPLIT;
                f16 h0 = (f16)v;
                float res = (v - (float)h0) * RSPLIT;
                Q0[(size_t)row * DM + col] = h0;
                Q1[(size_t)row * DM + col] = (f16)res;
            }
        }
}

// ---------- LDS-tiled bf16 MFMA GEMM (V / O projections) ---------------------
__global__ __launch_bounds__(256) void gemm_bf16_lds(
    const ushort_t* __restrict__ A, const ushort_t* __restrict__ BT,
    const float* __restrict__ bias, void* __restrict__ C, int cbf16,
    int Nn, int K)
{
    __shared__ __align__(16) ushort_t As[128][40];
    __shared__ __align__(16) ushort_t Bs[64][40];
    const int tid = threadIdx.x;
    const int wave = tid >> 6, lane = tid & 63;
    const int r = lane & 15, g = lane >> 4;
    const int row0 = blockIdx.y * 128;
    const int col0 = blockIdx.x * 64;
    f32x4 acc[2][4] = {};
    for (int k0 = 0; k0 < K; k0 += 32) {
        for (int idx = tid; idx < 128 * 4; idx += 256) {
            int row = idx >> 2, c = idx & 3;
            *(bf16x8*)&As[row][c * 8] = *(const bf16x8*)(A + (size_t)(row0 + row) * K + k0 + c * 8);
        }
        for (int idx = tid; idx < 64 * 4; idx += 256) {
            int row = idx >> 2, c = idx & 3;
            *(bf16x8*)&Bs[row][c * 8] = *(const bf16x8*)(BT + (size_t)(col0 + row) * K + k0 + c * 8);
        }
        __syncthreads();
        bf16x8 a[2], b[4];
#pragma unroll
        for (int rf = 0; rf < 2; ++rf)
            a[rf] = *(const bf16x8*)&As[wave * 32 + rf * 16 + r][g * 8];
#pragma unroll
        for (int cf = 0; cf < 4; ++cf)
            b[cf] = *(const bf16x8*)&Bs[cf * 16 + r][g * 8];
#pragma unroll
        for (int rf = 0; rf < 2; ++rf)
#pragma unroll
            for (int cf = 0; cf < 4; ++cf)
                acc[rf][cf] = MFMABF(a[rf], b[cf], acc[rf][cf]);
        __syncthreads();
    }
#pragma unroll
    for (int rf = 0; rf < 2; ++rf)
#pragma unroll
        for (int cf = 0; cf < 4; ++cf) {
            int col = col0 + cf * 16 + r;
            float bv = bias ? bias[col] : 0.f;
#pragma unroll
            for (int j = 0; j < 4; ++j) {
                int row = row0 + wave * 32 + rf * 16 + g * 4 + j;
                float vv = acc[rf][cf][j] + bv;
                if (cbf16) ((ushort_t*)C)[(size_t)row * Nn + col] = f2b(vv);
                else       ((float*)C)[(size_t)row * Nn + col] = vv;
            }
        }
}

// ---------- pass A: per-row sums of exp(S) for all heads ---------------------
// grid (CSB, NT/64, NH); no LDS; A-frags cached in regs across col tiles.
__global__ __launch_bounds__(256) void rowsum_kernel(
    const f16* __restrict__ Q0, const f16* __restrict__ Q1,
    const f16* __restrict__ K0, const f16* __restrict__ K1,
    float* __restrict__ partA)
{
    const int tid = threadIdx.x;
    const int wr = tid >> 6, lane = tid & 63;
    const int r = lane & 15, g = lane >> 4;
    const int cs = blockIdx.x;
    const int row0 = blockIdx.y * 64;
    const int h = blockIdx.z;
    const int hb = h * DH;
    const int arow = row0 + wr * 16 + r;
    f16x8 a0[3], a1[3];
#pragma unroll
    for (int ks = 0; ks < 3; ++ks) {
        f16x8 z = {};
        a0[ks] = z; a1[ks] = z;
        if ((ks < 2) || (g == 0)) {
            size_t o = (size_t)arow * DM + hb + ks * 32 + g * 8;
            a0[ks] = *(const f16x8*)(Q0 + o);
            a1[ks] = *(const f16x8*)(Q1 + o);
        }
    }
    float rs0 = 0.f, rs1 = 0.f, rs2 = 0.f, rs3 = 0.f;
    for (int ct = 0; ct < 8; ++ct) {
        const int colbase = cs * 512 + ct * 64;
        f32x4 accM[4] = {}, accC[4] = {};
#pragma unroll
        for (int ks = 0; ks < 3; ++ks) {
            const bool valid = (ks < 2) || (g == 0);
#pragma unroll
            for (int cf = 0; cf < 4; ++cf) {
                f16x8 b0 = {}, b1 = {};
                if (valid) {
                    size_t o = (size_t)(colbase + cf * 16 + r) * DM + hb + ks * 32 + g * 8;
                    b0 = *(const f16x8*)(K0 + o);
                    b1 = *(const f16x8*)(K1 + o);
                }
                accM[cf] = MFMA16(a0[ks], b0, accM[cf]);
                accC[cf] = MFMA16(a0[ks], b1, accC[cf]);
                accC[cf] = MFMA16(a1[ks], b0, accC[cf]);
            }
        }
#pragma unroll
        for (int cf = 0; cf < 4; ++cf) {
            rs0 += __expf((accM[cf][0] + accC[cf][0] * INV_RSPLIT) * SCALE);
            rs1 += __expf((accM[cf][1] + accC[cf][1] * INV_RSPLIT) * SCALE);
            rs2 += __expf((accM[cf][2] + accC[cf][2] * INV_RSPLIT) * SCALE);
            rs3 += __expf((accM[cf][3] + accC[cf][3] * INV_RSPLIT) * SCALE);
        }
    }
#pragma unroll
    for (int m = 1; m <= 8; m <<= 1) {
        rs0 += __shfl_xor(rs0, m);
        rs1 += __shfl_xor(rs1, m);
        rs2 += __shfl_xor(rs2, m);
        rs3 += __shfl_xor(rs3, m);
    }
    if (r == 0) {
        float* pp = partA + ((size_t)h * CSB + cs) * NT;
        int rbase = row0 + wr * 16 + g * 4;
        pp[rbase + 0] = rs0;
        pp[rbase + 1] = rs1;
        pp[rbase + 2] = rs2;
        pp[rbase + 3] = rs3;
    }
}

__global__ __launch_bounds__(256) void rowsum_reduce(
    const float* __restrict__ partA, float* __restrict__ invs)
{
    int idx = blockIdx.x * 256 + threadIdx.x;  // over NH*NT
    int h = idx >> 12, i = idx & (NT - 1);
    float s = 0.f;
#pragma unroll
    for (int cs = 0; cs < CSB; ++cs)
        s += partA[((size_t)h * CSB + cs) * NT + i];
    invs[idx] = 1.0f / s;
}

// ---------- pass B: fused QK^T -> P -> attn accumulate + PV ------------------
// grid (CSB, NT/64), per head; each WG: 64 rows x 512 cols.
__global__ __launch_bounds__(256) void fused_attn(
    const f16* __restrict__ Q0, const f16* __restrict__ Q1,
    const f16* __restrict__ K0, const f16* __restrict__ K1,
    const float* __restrict__ invs, const ushort_t* __restrict__ vtb,
    float* __restrict__ attn, float* __restrict__ part_pv,
    int h, int first)
{
    __shared__ ushort_t Pt[64][72];
    const int tid = threadIdx.x;
    const int wr = tid >> 6, lane = tid & 63;
    const int r = lane & 15, g = lane >> 4;
    const int cs = blockIdx.x;
    const int row0 = blockIdx.y * 64;
    const int hb = h * DH;
    const int arow = row0 + wr * 16 + r;
    f16x8 a0[3], a1[3];
#pragma unroll
    for (int ks = 0; ks < 3; ++ks) {
        f16x8 z = {};
        a0[ks] = z; a1[ks] = z;
        if ((ks < 2) || (g == 0)) {
            size_t o = (size_t)arow * DM + hb + ks * 32 + g * 8;
            a0[ks] = *(const f16x8*)(Q0 + o);
            a1[ks] = *(const f16x8*)(Q1 + o);
        }
    }
    float vinv[4];
#pragma unroll
    for (int j = 0; j < 4; ++j)
        vinv[j] = invs[(size_t)h * NT + row0 + wr * 16 + g * 4 + j];
    f32x4 oacc[5] = {};
    for (int ct = 0; ct < 8; ++ct) {
        const int colbase = cs * 512 + ct * 64;
        f32x4 accM[4] = {}, accC[4] = {};
#pragma unroll
        for (int ks = 0; ks < 3; ++ks) {
            const bool valid = (ks < 2) || (g == 0);
#pragma unroll
            for (int cf = 0; cf < 4; ++cf) {
                f16x8 b0 = {}, b1 = {};
                if (valid) {
                    size_t o = (size_t)(colbase + cf * 16 + r) * DM + hb + ks * 32 + g * 8;
                    b0 = *(const f16x8*)(K0 + o);
                    b1 = *(const f16x8*)(K1 + o);
                }
                accM[cf] = MFMA16(a0[ks], b0, accM[cf]);
                accC[cf] = MFMA16(a0[ks], b1, accC[cf]);
                accC[cf] = MFMA16(a1[ks], b0, accC[cf]);
            }
        }
#pragma unroll
        for (int cf = 0; cf < 4; ++cf) {
#pragma unroll
            for (int j = 0; j < 4; ++j) {
                float s = (accM[cf][j] + accC[cf][j] * INV_RSPLIT) * SCALE;
                float p = __expf(s) * vinv[j];
                int row = row0 + wr * 16 + g * 4 + j;
                size_t aoff = (size_t)row * NT + colbase + cf * 16 + r;
                if (first) attn[aoff] = p * 0.0625f;
                else       attn[aoff] += p * 0.0625f;
                Pt[wr * 16 + g * 4 + j][cf * 16 + r] = f2b(p);
            }
        }
        // PV: per-wave private LDS region; compiler inserts lgkm waits.
#pragma unroll
        for (int ks2 = 0; ks2 < 2; ++ks2) {
            bf16x8 pa = *(const bf16x8*)&Pt[wr * 16 + r][ks2 * 32 + g * 8];
#pragma unroll
            for (int t = 0; t < 5; ++t) {
                int col = t * 16 + r;
                bf16x8 b = {};
                if (col < DH)
                    b = *(const bf16x8*)(vtb + (size_t)(hb + col) * NT + colbase + ks2 * 32 + g * 8);
                oacc[t] = MFMABF(pa, b, oacc[t]);
            }
        }
    }
    float* pp = part_pv + (size_t)cs * NT * DH;
#pragma unroll
    for (int t = 0; t < 5; ++t) {
        int col = t * 16 + r;
        if (col < DH) {
#pragma unroll
            for (int j = 0; j < 4; ++j) {
                int row = row0 + wr * 16 + g * 4 + j;
                pp[(size_t)row * DH + col] = oacc[t][j];
            }
        }
    }
}

__global__ __launch_bounds__(256) void pv_reduce8(
    const float* __restrict__ part_pv, ushort_t* __restrict__ otmpb, int h)
{
    int idx = blockIdx.x * 256 + threadIdx.x;
    if (idx >= NT * DH) return;
    int row = idx / DH, col = idx - row * DH;
    float s = 0.f;
#pragma unroll
    for (int cs = 0; cs < CSB; ++cs) s += part_pv[(size_t)cs * NT * DH + idx];
    otmpb[(size_t)row * DM + h * DH + col] = f2b(s);
}

// ---------- pagerank power iteration (fp32, unchanged) -----------------------
__global__ __launch_bounds__(256) void init_dist(float* __restrict__ d)
{
    int t = blockIdx.x * 256 + threadIdx.x;
    if (t < NT) d[t] = 1.0f / NT;
}

__global__ __launch_bounds__(256) void power_a(
    const float* __restrict__ attn, const float* __restrict__ din,
    float* __restrict__ part)
{
    int j = blockIdx.x * 256 + threadIdx.x;
    int i0 = blockIdx.y * 128;
    float acc = 0.f;
    for (int i = i0; i < i0 + 128; ++i)
        acc += din[i] * attn[(size_t)i * NT + j];
    part[(size_t)blockIdx.y * NT + j] = acc;
}

__global__ __launch_bounds__(256) void power_b(
    const float* __restrict__ part, float* __restrict__ dout)
{
    int j = blockIdx.x * 256 + threadIdx.x;
    float acc = 0.f;
    for (int ib = 0; ib < 32; ++ib) acc += part[(size_t)ib * NT + j];
    dout[j] = acc;
}

// ---------- top-k: tiled rank counting (deterministic int atomics) -----------
__global__ __launch_bounds__(256) void rank_count(
    const float* __restrict__ imp, int* __restrict__ rank, int* __restrict__ prank)
{
    __shared__ float sj[256];
    const int tid = threadIdx.x;
    const int jb = blockIdx.y * 256;
    sj[tid] = imp[jb + tid];
    __syncthreads();
    const int i = blockIdx.x * 256 + tid;
    const float mv = imp[i];
    int r = 0, rp = 0;
    for (int jj = 0; jj < 256; ++jj) {
        float vj = sj[jj];
        int j = jb + jj;
        int tie_low = (vj == mv) && (j < i);
        r  += (vj > mv) || tie_low;
        rp += (vj < mv) || tie_low;
    }
    atomicAdd(&rank[i], r);
    atomicAdd(&prank[i], rp);
}

// ---------- single-block chunked scan scatter --------------------------------
__global__ __launch_bounds__(256) void scatter_topk2(
    const int* __restrict__ rank, const int* __restrict__ prank,
    float* __restrict__ out_imps, float* __restrict__ out_prune,
    int* __restrict__ imp_rows, int* __restrict__ prune_cols)
{
    __shared__ unsigned char fr[NT];
    __shared__ unsigned char fp[NT];
    __shared__ int sr[256], sp[256];
    const int tid = threadIdx.x;
    for (int t = tid; t < NT; t += 256) {
        fr[t] = rank[t] < KRET;
        fp[t] = prank[t] < NPR;
    }
    __syncthreads();
    const int base = tid * 16;
    int cr = 0, cp = 0;
#pragma unroll
    for (int e = 0; e < 16; ++e) { cr += fr[base + e]; cp += fp[base + e]; }
    sr[tid] = cr; sp[tid] = cp;
    __syncthreads();
    int pr = 0, pp = 0;
    for (int j = 0; j < tid; ++j) { pr += sr[j]; pp += sp[j]; }
#pragma unroll
    for (int e = 0; e < 16; ++e) {
        int i = base + e;
        if (fr[i]) { out_imps[pr] = (float)i; imp_rows[pr] = i; ++pr; }
        if (fp[i]) { out_prune[pp] = (float)i; prune_cols[pp] = i; ++pp; }
    }
}

// ---------- chunked per-column argmax over retained rows ---------------------
__global__ __launch_bounds__(256) void argmax_part(
    const float* __restrict__ attn, const int* __restrict__ imp_rows,
    float* __restrict__ pbest, int* __restrict__ pbi)
{
    __shared__ int rows[CHUNK];
    const int tid = threadIdx.x;
    const int rc = blockIdx.y;
    const int r0 = rc * CHUNK;
    const int nr = min(KRET - r0, CHUNK);
    for (int t = tid; t < nr; t += 256) rows[t] = imp_rows[r0 + t];
    __syncthreads();
    const int j = blockIdx.x * 256 + tid;
    float best = -INFINITY;
    int bi = 0;
    for (int rr = 0; rr < nr; ++rr) {
        float val = attn[(size_t)rows[rr] * NT + j];
        if (val > best) { best = val; bi = r0 + rr; }
    }
    pbest[(size_t)rc * NT + j] = best;
    pbi[(size_t)rc * NT + j] = bi;
}

__global__ __launch_bounds__(256) void argmax_red(
    const float* __restrict__ pbest, const int* __restrict__ pbi,
    int* __restrict__ maxind)
{
    const int j = blockIdx.x * 256 + threadIdx.x;
    float best = -INFINITY;
    int bi = 0;
#pragma unroll
    for (int rc = 0; rc < 8; ++rc) {
        float val = pbest[(size_t)rc * NT + j];
        if (val > best) { best = val; bi = pbi[(size_t)rc * NT + j]; }
    }
    maxind[j] = bi;
}

__global__ __launch_bounds__(256) void finalize(
    const float* __restrict__ dist, const int* __restrict__ prune_cols,
    const int* __restrict__ maxind, float* __restrict__ out_imp,
    float* __restrict__ out_simi)
{
    int t = blockIdx.x * 256 + threadIdx.x;
    if (t < NT) out_imp[t] = dist[t];
    if (t < NPR) out_simi[t] = (float)maxind[prune_cols[t]];
}

extern "C" void kernel_launch(void* const* d_in, const int* in_sizes, int n_in,
                              void* d_out, int out_size, void* d_ws, size_t ws_size,
                              hipStream_t stream)
{
    const float* x  = (const float*)d_in[0];
    const float* Wq = (const float*)d_in[1];
    const float* Wk = (const float*)d_in[2];
    const float* Wv = (const float*)d_in[3];
    const float* Wo = (const float*)d_in[4];
    const float* bo = (const float*)d_in[5];
    float* out = (float*)d_out;

    // ---- workspace layout (float units), ~164 MB ----
    float* ws = (float*)d_ws;
    size_t off = 0;
    float* attn = ws + off; off += (size_t)NT * NT;          // 16.78M fl
    f16* Q0 = (f16*)(ws + off); f16* Q1 = Q0 + (size_t)NT * DM; off += (size_t)NT * DM;
    f16* K0 = (f16*)(ws + off); f16* K1 = K0 + (size_t)NT * DM; off += (size_t)NT * DM;
    f16* X0 = (f16*)(ws + off); f16* X1 = X0 + (size_t)NT * DM; off += (size_t)NT * DM;
    f16* T0 = (f16*)(ws + off); f16* T1 = T0 + (size_t)DM * DM; off += (size_t)DM * DM;
    ushort_t* Wslot = (ushort_t*)(ws + off); off += ((size_t)DM * DM) / 2;
    ushort_t* vtb   = (ushort_t*)(ws + off); off += ((size_t)NT * DM) / 2;
    ushort_t* otmpb = (ushort_t*)(ws + off); off += ((size_t)NT * DM) / 2;
    float* partA   = ws + off; off += (size_t)NH * CSB * NT;
    float* invs    = ws + off; off += (size_t)NH * NT;
    float* part_pv = ws + off; off += (size_t)CSB * NT * DH;
    float* pbest   = ws + off; off += 8 * NT;
    int*   pbi     = (int*)(ws + off); off += 8 * NT;
    float* dist0 = ws + off; off += NT;
    float* dist1 = ws + off; off += NT;
    float* partial = ws + off; off += 32 * NT;
    int* rank      = (int*)(ws + off); off += NT;
    int* prank     = (int*)(ws + off); off += NT;
    int* imp_rows  = (int*)(ws + off); off += 2048;
    int* prune_cols= (int*)(ws + off); off += 2560;
    int* maxind    = (int*)(ws + off); off += NT;

    // setup-only aliases inside attn region (dead before fused_attn h==0 writes)
    ushort_t* xb = (ushort_t*)attn;
    ushort_t* vb = (ushort_t*)(attn + (size_t)NT * DM / 2);

    // output layout
    float* out_out   = out;
    float* out_imp   = out + (size_t)NT * DM;
    float* out_imps  = out_imp + NT;
    float* out_prune = out_imps + KRET;
    float* out_simi  = out_prune + NPR;

    // ---- setup: splits + projections ----
    split_x<<<2048, 256, 0, stream>>>(x, X0, X1, xb, NT * DM);

    dim3 gT(DM / 32, DM / 32);
    dim3 gP(DM / 64, NT / 128);
    transposeW_split<<<gT, 256, 0, stream>>>(Wq, T0, T1, DM);
    proj_split2<<<gP, 256, 0, stream>>>(X0, X1, T0, T1, Q0, Q1);
    transposeW_split<<<gT, 256, 0, stream>>>(Wk, T0, T1, DM);
    proj_split2<<<gP, 256, 0, stream>>>(X0, X1, T0, T1, K0, K1);

    transposeW_bf16<<<gT, 256, 0, stream>>>(Wv, Wslot, DM);
    gemm_bf16_lds<<<gP, 256, 0, stream>>>(xb, Wslot, nullptr, vb, 1, DM, DM);
    transposeB16<<<dim3(DM / 32, NT / 32), 256, 0, stream>>>(vb, vtb, NT, DM);

    // ---- pass A: row sums for all heads ----
    rowsum_kernel<<<dim3(CSB, NT / 64, NH), 256, 0, stream>>>(Q0, Q1, K0, K1, partA);
    rowsum_reduce<<<(NH * NT) / 256, 256, 0, stream>>>(partA, invs);

    // ---- pass B: fused attention per head ----
    for (int h = 0; h < NH; ++h) {
        fused_attn<<<dim3(CSB, NT / 64), 256, 0, stream>>>(
            Q0, Q1, K0, K1, invs, vtb, attn, part_pv, h, h == 0 ? 1 : 0);
        pv_reduce8<<<(NT * DH) / 256, 256, 0, stream>>>(part_pv, otmpb, h);
    }

    // ---- output projection ----
    transposeW_bf16<<<gT, 256, 0, stream>>>(Wo, Wslot, DM);
    gemm_bf16_lds<<<gP, 256, 0, stream>>>(otmpb, Wslot, bo, out_out, 0, DM, DM);

    // ---- pagerank ----
    init_dist<<<16, 256, 0, stream>>>(dist0);
    float* da = dist0;
    float* db = dist1;
    for (int it = 0; it < 5; ++it) {
        power_a<<<dim3(16, 32), 256, 0, stream>>>(attn, da, partial);
        power_b<<<16, 256, 0, stream>>>(partial, db);
        float* t = da; da = db; db = t;
    }

    // ---- top-k ----
    hipMemsetAsync(rank, 0, 2 * NT * sizeof(int), stream);
    rank_count<<<dim3(16, 16), 256, 0, stream>>>(da, rank, prank);
    scatter_topk2<<<1, 256, 0, stream>>>(rank, prank, out_imps, out_prune,
                                         imp_rows, prune_cols);
    argmax_part<<<dim3(16, 8), 256, 0, stream>>>(attn, imp_rows, pbest, pbi);
    argmax_red<<<16, 256, 0, stream>>>(pbest, pbi, maxind);
    finalize<<<16, 256, 0, stream>>>(da, prune_cols, maxind, out_imp, out_simi);
}

// Round 6
// 1579.267 us; speedup vs baseline: 1.5761x; 1.5761x over previous
//
#include <hip/hip_runtime.h>
#include <math.h>

#define NT 4096
#define DM 1152
#define NH 16
#define DH 72
#define KRET 1638
#define NPR (NT - KRET)
#define CSB 8
#define CHUNK 205
#define SCALE 0.11785113019775793f
#define RSPLIT 2048.0f
#define INV_RSPLIT 4.8828125e-4f

typedef __attribute__((ext_vector_type(8))) short bf16x8;
typedef _Float16 f16;
typedef __attribute__((ext_vector_type(8))) _Float16 f16x8;
typedef __attribute__((ext_vector_type(4))) float f32x4;
typedef unsigned short ushort_t;

#define MFMA16(a, b, c) __builtin_amdgcn_mfma_f32_16x16x32_f16(a, b, c, 0, 0, 0)
#define MFMABF(a, b, c) __builtin_amdgcn_mfma_f32_16x16x32_bf16(a, b, c, 0, 0, 0)

__device__ inline ushort_t f2b(float f) {
    union { float f; unsigned int u; } v; v.f = f;
    unsigned int u = v.u;
    return (ushort_t)((u + 0x7FFFu + ((u >> 16) & 1u)) >> 16);
}

// tiled Q/K address: [NH][rowblk 256][ks 3][r 16][ki 32]
__device__ inline size_t qkAddr(int h, int row, int ks, int ki) {
    return ((((size_t)h * 256 + (row >> 4)) * 3 + ks) * 16 + (row & 15)) * 32 + ki;
}

// ---------- split x into fp16 hi/lo(x2048) planes + bf16 copy ----------------
__global__ __launch_bounds__(256) void split_x(
    const float* __restrict__ in, f16* __restrict__ x0, f16* __restrict__ x1,
    ushort_t* __restrict__ xb, int nElem)
{
    int i = blockIdx.x * 256 + threadIdx.x;
    int stride = gridDim.x * 256;
    for (; i < nElem; i += stride) {
        float v = in[i];
        f16 h0 = (f16)v;
        float res = (v - (float)h0) * RSPLIT;
        x0[i] = h0;
        x1[i] = (f16)res;
        xb[i] = f2b(v);
    }
}

__global__ __launch_bounds__(256) void transposeW_split(
    const float* __restrict__ W, f16* __restrict__ T0, f16* __restrict__ T1, int n)
{
    __shared__ float t[32][33];
    int bx = blockIdx.x * 32, by = blockIdx.y * 32;
    int tx = threadIdx.x & 31, ty = threadIdx.x >> 5;
    for (int i = ty; i < 32; i += 8)
        t[i][tx] = W[(size_t)(by + i) * n + bx + tx];
    __syncthreads();
    for (int i = ty; i < 32; i += 8) {
        float v = t[tx][i];
        f16 h0 = (f16)v;
        float res = (v - (float)h0) * RSPLIT;
        T0[(size_t)(bx + i) * n + by + tx] = h0;
        T1[(size_t)(bx + i) * n + by + tx] = (f16)res;
    }
}

__global__ __launch_bounds__(256) void transposeW_bf16(
    const float* __restrict__ W, ushort_t* __restrict__ WT, int n)
{
    __shared__ ushort_t t[32][33];
    int bx = blockIdx.x * 32, by = blockIdx.y * 32;
    int tx = threadIdx.x & 31, ty = threadIdx.x >> 5;
    for (int i = ty; i < 32; i += 8)
        t[i][tx] = f2b(W[(size_t)(by + i) * n + bx + tx]);
    __syncthreads();
    for (int i = ty; i < 32; i += 8)
        WT[(size_t)(bx + i) * n + by + tx] = t[tx][i];
}

// ---------- LDS-tiled split projection -> MFMA-tiled per-head output ---------
__global__ __launch_bounds__(256) void proj_split3(
    const f16* __restrict__ A0, const f16* __restrict__ A1,
    const f16* __restrict__ B0, const f16* __restrict__ B1,
    f16* __restrict__ Qt0, f16* __restrict__ Qt1)
{
    __shared__ __align__(16) f16 As0[128][40];
    __shared__ __align__(16) f16 As1[128][40];
    __shared__ __align__(16) f16 Bs0[64][40];
    __shared__ __align__(16) f16 Bs1[64][40];
    const int tid = threadIdx.x;
    const int wave = tid >> 6, lane = tid & 63;
    const int r = lane & 15, g = lane >> 4;
    const int row0 = blockIdx.y * 128;
    const int col0 = blockIdx.x * 64;
    f32x4 accM[2][4] = {}, accC[2][4] = {};
    for (int k0 = 0; k0 < DM; k0 += 32) {
        for (int idx = tid; idx < 128 * 4; idx += 256) {
            int row = idx >> 2, c = idx & 3;
            size_t src = (size_t)(row0 + row) * DM + k0 + c * 8;
            *(f16x8*)&As0[row][c * 8] = *(const f16x8*)(A0 + src);
            *(f16x8*)&As1[row][c * 8] = *(const f16x8*)(A1 + src);
        }
        for (int idx = tid; idx < 64 * 4; idx += 256) {
            int row = idx >> 2, c = idx & 3;
            size_t src = (size_t)(col0 + row) * DM + k0 + c * 8;
            *(f16x8*)&Bs0[row][c * 8] = *(const f16x8*)(B0 + src);
            *(f16x8*)&Bs1[row][c * 8] = *(const f16x8*)(B1 + src);
        }
        __syncthreads();
        f16x8 a0[2], a1[2], b0[4], b1[4];
#pragma unroll
        for (int rf = 0; rf < 2; ++rf) {
            a0[rf] = *(const f16x8*)&As0[wave * 32 + rf * 16 + r][g * 8];
            a1[rf] = *(const f16x8*)&As1[wave * 32 + rf * 16 + r][g * 8];
        }
#pragma unroll
        for (int cf = 0; cf < 4; ++cf) {
            b0[cf] = *(const f16x8*)&Bs0[cf * 16 + r][g * 8];
            b1[cf] = *(const f16x8*)&Bs1[cf * 16 + r][g * 8];
        }
#pragma unroll
        for (int rf = 0; rf < 2; ++rf)
#pragma unroll
            for (int cf = 0; cf < 4; ++cf) {
                accM[rf][cf] = MFMA16(a0[rf], b0[cf], accM[rf][cf]);
                accC[rf][cf] = MFMA16(a0[rf], b1[cf], accC[rf][cf]);
                accC[rf][cf] = MFMA16(a1[rf], b0[cf], accC[rf][cf]);
            }
        __syncthreads();
    }
#pragma unroll
    for (int rf = 0; rf < 2; ++rf)
#pragma unroll
        for (int cf = 0; cf < 4; ++cf) {
            int col = col0 + cf * 16 + r;
            int head = col / DH;
            int c = col - head * DH;
            int ks = c >> 5, ki = c & 31;
#pragma unroll
            for (int j = 0; j < 4; ++j) {
                int row = row0 + wave * 32 + rf * 16 + g * 4 + j;
                float v = accM[rf][cf][j] + accC[rf][cf][j] * INV_RSPLIT;
                f16 h0 = (f16)v;
                float res = (v - (float)h0) * RSPLIT;
                size_t addr = qkAddr(head, row, ks, ki);
                Qt0[addr] = h0;
                Qt1[addr] = (f16)res;
            }
        }
}

// ---------- LDS-tiled bf16 MFMA GEMM; mode 0 = fp32 flat, 2 = Vp tiled -------
__global__ __launch_bounds__(256) void gemm_bf16_lds(
    const ushort_t* __restrict__ A, const ushort_t* __restrict__ BT,
    const float* __restrict__ bias, void* __restrict__ C, int mode,
    int Nn, int K)
{
    __shared__ __align__(16) ushort_t As[128][40];
    __shared__ __align__(16) ushort_t Bs[64][40];
    const int tid = threadIdx.x;
    const int wave = tid >> 6, lane = tid & 63;
    const int r = lane & 15, g = lane >> 4;
    const int row0 = blockIdx.y * 128;
    const int col0 = blockIdx.x * 64;
    f32x4 acc[2][4] = {};
    for (int k0 = 0; k0 < K; k0 += 32) {
        for (int idx = tid; idx < 128 * 4; idx += 256) {
            int row = idx >> 2, c = idx & 3;
            *(bf16x8*)&As[row][c * 8] = *(const bf16x8*)(A + (size_t)(row0 + row) * K + k0 + c * 8);
        }
        for (int idx = tid; idx < 64 * 4; idx += 256) {
            int row = idx >> 2, c = idx & 3;
            *(bf16x8*)&Bs[row][c * 8] = *(const bf16x8*)(BT + (size_t)(col0 + row) * K + k0 + c * 8);
        }
        __syncthreads();
        bf16x8 a[2], b[4];
#pragma unroll
        for (int rf = 0; rf < 2; ++rf)
            a[rf] = *(const bf16x8*)&As[wave * 32 + rf * 16 + r][g * 8];
#pragma unroll
        for (int cf = 0; cf < 4; ++cf)
            b[cf] = *(const bf16x8*)&Bs[cf * 16 + r][g * 8];
#pragma unroll
        for (int rf = 0; rf < 2; ++rf)
#pragma unroll
            for (int cf = 0; cf < 4; ++cf)
                acc[rf][cf] = MFMABF(a[rf], b[cf], acc[rf][cf]);
        __syncthreads();
    }
#pragma unroll
    for (int rf = 0; rf < 2; ++rf)
#pragma unroll
        for (int cf = 0; cf < 4; ++cf) {
            int col = col0 + cf * 16 + r;
            float bv = bias ? bias[col] : 0.f;
#pragma unroll
            for (int j = 0; j < 4; ++j) {
                int row = row0 + wave * 32 + rf * 16 + g * 4 + j;
                float vv = acc[rf][cf][j] + bv;
                if (mode == 2) {
                    int head = col / DH;
                    int d = col - head * DH;
                    size_t addr = (((size_t)head * 128 + (row >> 5)) * 80 + d) * 32 + (row & 31);
                    ((ushort_t*)C)[addr] = f2b(vv);
                } else {
                    ((float*)C)[(size_t)row * Nn + col] = vv;
                }
            }
        }
}

// ---------- pass A: per-row 1/rowsum of exp(S), all heads, tiled loads -------
__global__ __launch_bounds__(512) void rowsum3(
    const f16* __restrict__ Qt0, const f16* __restrict__ Qt1,
    const f16* __restrict__ Kt0, const f16* __restrict__ Kt1,
    float* __restrict__ invs)
{
    const int tid = threadIdx.x;
    const int wv = tid >> 6, lane = tid & 63;
    const int r = lane & 15, g = lane >> 4;
    const int h = blockIdx.y;
    const int rowblk = blockIdx.x * 8 + wv;
    f16x8 a0[3], a1[3];
#pragma unroll
    for (int ks = 0; ks < 3; ++ks) {
        size_t o = ((((size_t)h * 256 + rowblk) * 3 + ks) * 16) * 32 + r * 32 + g * 8;
        a0[ks] = *(const f16x8*)(Qt0 + o);
        a1[ks] = *(const f16x8*)(Qt1 + o);
    }
    float rs0 = 0.f, rs1 = 0.f, rs2 = 0.f, rs3 = 0.f;
    for (int ct = 0; ct < 64; ++ct) {
        f32x4 accM[4] = {}, accC[4] = {};
#pragma unroll
        for (int ks = 0; ks < 3; ++ks) {
#pragma unroll
            for (int cf = 0; cf < 4; ++cf) {
                int colblk = ct * 4 + cf;
                size_t o = ((((size_t)h * 256 + colblk) * 3 + ks) * 16) * 32 + r * 32 + g * 8;
                f16x8 b0 = *(const f16x8*)(Kt0 + o);
                f16x8 b1 = *(const f16x8*)(Kt1 + o);
                accM[cf] = MFMA16(a0[ks], b0, accM[cf]);
                accC[cf] = MFMA16(a0[ks], b1, accC[cf]);
                accC[cf] = MFMA16(a1[ks], b0, accC[cf]);
            }
        }
#pragma unroll
        for (int cf = 0; cf < 4; ++cf) {
            rs0 += __expf((accM[cf][0] + accC[cf][0] * INV_RSPLIT) * SCALE);
            rs1 += __expf((accM[cf][1] + accC[cf][1] * INV_RSPLIT) * SCALE);
            rs2 += __expf((accM[cf][2] + accC[cf][2] * INV_RSPLIT) * SCALE);
            rs3 += __expf((accM[cf][3] + accC[cf][3] * INV_RSPLIT) * SCALE);
        }
    }
#pragma unroll
    for (int m = 1; m <= 8; m <<= 1) {
        rs0 += __shfl_xor(rs0, m);
        rs1 += __shfl_xor(rs1, m);
        rs2 += __shfl_xor(rs2, m);
        rs3 += __shfl_xor(rs3, m);
    }
    if (r == 0) {
        int rbase = rowblk * 16 + g * 4;
        invs[(size_t)h * NT + rbase + 0] = 1.0f / rs0;
        invs[(size_t)h * NT + rbase + 1] = 1.0f / rs1;
        invs[(size_t)h * NT + rbase + 2] = 1.0f / rs2;
        invs[(size_t)h * NT + rbase + 3] = 1.0f / rs3;
    }
}

// ---------- pass B: fused QK^T->P->attn(+pair)->PV, 2 heads per launch -------
__global__ __launch_bounds__(256) void fused3(
    const f16* __restrict__ Qt0, const f16* __restrict__ Qt1,
    const f16* __restrict__ Kt0, const f16* __restrict__ Kt1,
    const float* __restrict__ invs, const ushort_t* __restrict__ Vp,
    float* __restrict__ attn, float* __restrict__ part_pv,
    int hpair, int first)
{
    __shared__ ushort_t Pt[64][88];
    const int tid = threadIdx.x;
    const int wr = tid >> 6, lane = tid & 63;
    const int r = lane & 15, g = lane >> 4;
    const int cs = blockIdx.x;
    const int rowblk = blockIdx.y * 4 + wr;
    const int row0 = rowblk * 16;
    f16x8 a0[2][3], a1[2][3];
    float vinv[2][4];
    f32x4 oacc[2][5] = {};
#pragma unroll
    for (int hh = 0; hh < 2; ++hh) {
        int h = hpair * 2 + hh;
#pragma unroll
        for (int ks = 0; ks < 3; ++ks) {
            size_t o = ((((size_t)h * 256 + rowblk) * 3 + ks) * 16) * 32 + r * 32 + g * 8;
            a0[hh][ks] = *(const f16x8*)(Qt0 + o);
            a1[hh][ks] = *(const f16x8*)(Qt1 + o);
        }
#pragma unroll
        for (int j = 0; j < 4; ++j)
            vinv[hh][j] = invs[(size_t)h * NT + row0 + g * 4 + j];
    }
    for (int ct = 0; ct < 8; ++ct) {
        const int colbase = cs * 512 + ct * 64;
        float P0[4][4];
#pragma unroll
        for (int hh = 0; hh < 2; ++hh) {
            const int h = hpair * 2 + hh;
            f32x4 accM[4] = {}, accC[4] = {};
#pragma unroll
            for (int ks = 0; ks < 3; ++ks) {
#pragma unroll
                for (int cf = 0; cf < 4; ++cf) {
                    int colblk = (colbase >> 4) + cf;
                    size_t o = ((((size_t)h * 256 + colblk) * 3 + ks) * 16) * 32 + r * 32 + g * 8;
                    f16x8 b0 = *(const f16x8*)(Kt0 + o);
                    f16x8 b1 = *(const f16x8*)(Kt1 + o);
                    accM[cf] = MFMA16(a0[hh][ks], b0, accM[cf]);
                    accC[cf] = MFMA16(a0[hh][ks], b1, accC[cf]);
                    accC[cf] = MFMA16(a1[hh][ks], b0, accC[cf]);
                }
            }
#pragma unroll
            for (int cf = 0; cf < 4; ++cf) {
#pragma unroll
                for (int j = 0; j < 4; ++j) {
                    float s = (accM[cf][j] + accC[cf][j] * INV_RSPLIT) * SCALE;
                    float p = __expf(s) * vinv[hh][j];
                    Pt[wr * 16 + g * 4 + j][cf * 16 + r] = f2b(p);
                    if (hh == 0) {
                        P0[cf][j] = p;
                    } else {
                        int row = row0 + g * 4 + j;
                        size_t aoff = (size_t)row * NT + colbase + cf * 16 + r;
                        float av = (P0[cf][j] + p) * 0.0625f;
                        if (first) attn[aoff] = av;
                        else       attn[aoff] += av;
                    }
                }
            }
            const int kt0 = colbase >> 5;
#pragma unroll
            for (int ks2 = 0; ks2 < 2; ++ks2) {
                bf16x8 pa = *(const bf16x8*)&Pt[wr * 16 + r][ks2 * 32 + g * 8];
#pragma unroll
                for (int t = 0; t < 5; ++t) {
                    int col = t * 16 + r;
                    size_t vo = (((size_t)h * 128 + kt0 + ks2) * 80 + col) * 32 + g * 8;
                    bf16x8 b = *(const bf16x8*)(Vp + vo);
                    oacc[hh][t] = MFMABF(pa, b, oacc[hh][t]);
                }
            }
        }
    }
#pragma unroll
    for (int hh = 0; hh < 2; ++hh)
#pragma unroll
        for (int t = 0; t < 5; ++t) {
            int col = t * 16 + r;
            if (col < DH) {
#pragma unroll
                for (int j = 0; j < 4; ++j) {
                    int row = row0 + g * 4 + j;
                    part_pv[(((size_t)cs * 2 + hh) * NT + row) * DH + col] = oacc[hh][t][j];
                }
            }
        }
}

__global__ __launch_bounds__(256) void pv_reduce2h(
    const float* __restrict__ part_pv, ushort_t* __restrict__ otmpb, int hpair)
{
    int idx = blockIdx.x * 256 + threadIdx.x;
    if (idx >= 2 * NT * DH) return;
    int hh = idx / (NT * DH);
    int rem = idx - hh * NT * DH;
    int row = rem / DH, col = rem - row * DH;
    float s = 0.f;
#pragma unroll
    for (int cs = 0; cs < CSB; ++cs)
        s += part_pv[(((size_t)cs * 2 + hh) * NT + row) * DH + col];
    otmpb[(size_t)row * DM + (hpair * 2 + hh) * DH + col] = f2b(s);
}

// ---------- pagerank power iteration (fp32, unchanged) -----------------------
__global__ __launch_bounds__(256) void init_dist(float* __restrict__ d)
{
    int t = blockIdx.x * 256 + threadIdx.x;
    if (t < NT) d[t] = 1.0f / NT;
}

__global__ __launch_bounds__(256) void power_a(
    const float* __restrict__ attn, const float* __restrict__ din,
    float* __restrict__ part)
{
    int j = blockIdx.x * 256 + threadIdx.x;
    int i0 = blockIdx.y * 128;
    float acc = 0.f;
    for (int i = i0; i < i0 + 128; ++i)
        acc += din[i] * attn[(size_t)i * NT + j];
    part[(size_t)blockIdx.y * NT + j] = acc;
}

__global__ __launch_bounds__(256) void power_b(
    const float* __restrict__ part, float* __restrict__ dout)
{
    int j = blockIdx.x * 256 + threadIdx.x;
    float acc = 0.f;
    for (int ib = 0; ib < 32; ++ib) acc += part[(size_t)ib * NT + j];
    dout[j] = acc;
}

// ---------- top-k: tiled rank counting (deterministic int atomics) -----------
__global__ __launch_bounds__(256) void rank_count(
    const float* __restrict__ imp, int* __restrict__ rank, int* __restrict__ prank)
{
    __shared__ float sj[256];
    const int tid = threadIdx.x;
    const int jb = blockIdx.y * 256;
    sj[tid] = imp[jb + tid];
    __syncthreads();
    const int i = blockIdx.x * 256 + tid;
    const float mv = imp[i];
    int r = 0, rp = 0;
    for (int jj = 0; jj < 256; ++jj) {
        float vj = sj[jj];
        int j = jb + jj;
        int tie_low = (vj == mv) && (j < i);
        r  += (vj > mv) || tie_low;
        rp += (vj < mv) || tie_low;
    }
    atomicAdd(&rank[i], r);
    atomicAdd(&prank[i], rp);
}

__global__ __launch_bounds__(256) void scatter_topk2(
    const int* __restrict__ rank, const int* __restrict__ prank,
    float* __restrict__ out_imps, float* __restrict__ out_prune,
    int* __restrict__ imp_rows, int* __restrict__ prune_cols)
{
    __shared__ unsigned char fr[NT];
    __shared__ unsigned char fp[NT];
    __shared__ int sr[256], sp[256];
    const int tid = threadIdx.x;
    for (int t = tid; t < NT; t += 256) {
        fr[t] = rank[t] < KRET;
        fp[t] = prank[t] < NPR;
    }
    __syncthreads();
    const int base = tid * 16;
    int cr = 0, cp = 0;
#pragma unroll
    for (int e = 0; e < 16; ++e) { cr += fr[base + e]; cp += fp[base + e]; }
    sr[tid] = cr; sp[tid] = cp;
    __syncthreads();
    int pr = 0, pp = 0;
    for (int j = 0; j < tid; ++j) { pr += sr[j]; pp += sp[j]; }
#pragma unroll
    for (int e = 0; e < 16; ++e) {
        int i = base + e;
        if (fr[i]) { out_imps[pr] = (float)i; imp_rows[pr] = i; ++pr; }
        if (fp[i]) { out_prune[pp] = (float)i; prune_cols[pp] = i; ++pp; }
    }
}

__global__ __launch_bounds__(256) void argmax_part(
    const float* __restrict__ attn, const int* __restrict__ imp_rows,
    float* __restrict__ pbest, int* __restrict__ pbi)
{
    __shared__ int rows[CHUNK];
    const int tid = threadIdx.x;
    const int rc = blockIdx.y;
    const int r0 = rc * CHUNK;
    const int nr = min(KRET - r0, CHUNK);
    for (int t = tid; t < nr; t += 256) rows[t] = imp_rows[r0 + t];
    __syncthreads();
    const int j = blockIdx.x * 256 + tid;
    float best = -INFINITY;
    int bi = 0;
    for (int rr = 0; rr < nr; ++rr) {
        float val = attn[(size_t)rows[rr] * NT + j];
        if (val > best) { best = val; bi = r0 + rr; }
    }
    pbest[(size_t)rc * NT + j] = best;
    pbi[(size_t)rc * NT + j] = bi;
}

__global__ __launch_bounds__(256) void argmax_red(
    const float* __restrict__ pbest, const int* __restrict__ pbi,
    int* __restrict__ maxind)
{
    const int j = blockIdx.x * 256 + threadIdx.x;
    float best = -INFINITY;
    int bi = 0;
#pragma unroll
    for (int rc = 0; rc < 8; ++rc) {
        float val = pbest[(size_t)rc * NT + j];
        if (val > best) { best = val; bi = pbi[(size_t)rc * NT + j]; }
    }
    maxind[j] = bi;
}

__global__ __launch_bounds__(256) void finalize(
    const float* __restrict__ dist, const int* __restrict__ prune_cols,
    const int* __restrict__ maxind, float* __restrict__ out_imp,
    float* __restrict__ out_simi)
{
    int t = blockIdx.x * 256 + threadIdx.x;
    if (t < NT) out_imp[t] = dist[t];
    if (t < NPR) out_simi[t] = (float)maxind[prune_cols[t]];
}

extern "C" void kernel_launch(void* const* d_in, const int* in_sizes, int n_in,
                              void* d_out, int out_size, void* d_ws, size_t ws_size,
                              hipStream_t stream)
{
    const float* x  = (const float*)d_in[0];
    const float* Wq = (const float*)d_in[1];
    const float* Wk = (const float*)d_in[2];
    const float* Wv = (const float*)d_in[3];
    const float* Wo = (const float*)d_in[4];
    const float* bo = (const float*)d_in[5];
    float* out = (float*)d_out;

    const size_t QKT_EL = (size_t)NH * 256 * 3 * 16 * 32;   // 6.29M f16 per plane
    const size_t VP_EL  = (size_t)NH * 128 * 80 * 32;       // 5.24M bf16

    // ---- workspace layout (float units), ~180 MB ----
    float* ws = (float*)d_ws;
    size_t off = 0;
    float* attn = ws + off; off += (size_t)NT * NT;
    f16* Qt0 = (f16*)(ws + off); off += QKT_EL / 2;
    f16* Qt1 = (f16*)(ws + off); off += QKT_EL / 2;
    f16* Kt0 = (f16*)(ws + off); off += QKT_EL / 2;
    f16* Kt1 = (f16*)(ws + off); off += QKT_EL / 2;
    ushort_t* Vp = (ushort_t*)(ws + off); off += VP_EL / 2;
    size_t zero_floats = 4 * (QKT_EL / 2) + VP_EL / 2;      // Qt0..Vp contiguous
    ushort_t* otmpb = (ushort_t*)(ws + off); off += ((size_t)NT * DM) / 2;
    f16* X0 = (f16*)(ws + off); f16* X1 = X0 + (size_t)NT * DM; off += (size_t)NT * DM;
    f16* T0 = (f16*)(ws + off); f16* T1 = T0 + (size_t)DM * DM; off += (size_t)DM * DM;
    ushort_t* Wslot = (ushort_t*)(ws + off); off += ((size_t)DM * DM) / 2;
    float* invs    = ws + off; off += (size_t)NH * NT;
    float* part_pv = ws + off; off += (size_t)CSB * 2 * NT * DH;
    float* pbest   = ws + off; off += 8 * NT;
    int*   pbi     = (int*)(ws + off); off += 8 * NT;
    float* dist0 = ws + off; off += NT;
    float* dist1 = ws + off; off += NT;
    float* partial = ws + off; off += 32 * NT;
    int* rank      = (int*)(ws + off); off += NT;
    int* prank     = (int*)(ws + off); off += NT;
    int* imp_rows  = (int*)(ws + off); off += 2048;
    int* prune_cols= (int*)(ws + off); off += 2560;
    int* maxind    = (int*)(ws + off); off += NT;

    // setup-only alias inside attn region (dead before fused3 pair0 writes)
    ushort_t* xb = (ushort_t*)attn;

    // output layout
    float* out_out   = out;
    float* out_imp   = out + (size_t)NT * DM;
    float* out_imps  = out_imp + NT;
    float* out_prune = out_imps + KRET;
    float* out_simi  = out_prune + NPR;

    // ---- setup ----
    hipMemsetAsync(Qt0, 0, zero_floats * sizeof(float), stream);  // zero-pad tiles
    split_x<<<2048, 256, 0, stream>>>(x, X0, X1, xb, NT * DM);

    dim3 gT(DM / 32, DM / 32);
    dim3 gP(DM / 64, NT / 128);
    transposeW_split<<<gT, 256, 0, stream>>>(Wq, T0, T1, DM);
    proj_split3<<<gP, 256, 0, stream>>>(X0, X1, T0, T1, Qt0, Qt1);
    transposeW_split<<<gT, 256, 0, stream>>>(Wk, T0, T1, DM);
    proj_split3<<<gP, 256, 0, stream>>>(X0, X1, T0, T1, Kt0, Kt1);

    transposeW_bf16<<<gT, 256, 0, stream>>>(Wv, Wslot, DM);
    gemm_bf16_lds<<<gP, 256, 0, stream>>>(xb, Wslot, nullptr, Vp, 2, DM, DM);

    // ---- pass A: inverse row sums ----
    rowsum3<<<dim3(NT / 128, NH), 512, 0, stream>>>(Qt0, Qt1, Kt0, Kt1, invs);

    // ---- pass B: fused attention, 2 heads per launch ----
    for (int hp = 0; hp < NH / 2; ++hp) {
        fused3<<<dim3(CSB, NT / 64), 256, 0, stream>>>(
            Qt0, Qt1, Kt0, Kt1, invs, Vp, attn, part_pv, hp, hp == 0 ? 1 : 0);
        pv_reduce2h<<<(2 * NT * DH + 255) / 256, 256, 0, stream>>>(part_pv, otmpb, hp);
    }

    // ---- output projection ----
    transposeW_bf16<<<gT, 256, 0, stream>>>(Wo, Wslot, DM);
    gemm_bf16_lds<<<gP, 256, 0, stream>>>(otmpb, Wslot, bo, out_out, 0, DM, DM);

    // ---- pagerank ----
    init_dist<<<16, 256, 0, stream>>>(dist0);
    float* da = dist0;
    float* db = dist1;
    for (int it = 0; it < 5; ++it) {
        power_a<<<dim3(16, 32), 256, 0, stream>>>(attn, da, partial);
        power_b<<<16, 256, 0, stream>>>(partial, db);
        float* t = da; da = db; db = t;
    }

    // ---- top-k ----
    hipMemsetAsync(rank, 0, 2 * NT * sizeof(int), stream);
    rank_count<<<dim3(16, 16), 256, 0, stream>>>(da, rank, prank);
    scatter_topk2<<<1, 256, 0, stream>>>(rank, prank, out_imps, out_prune,
                                         imp_rows, prune_cols);
    argmax_part<<<dim3(16, 8), 256, 0, stream>>>(attn, imp_rows, pbest, pbi);
    argmax_red<<<16, 256, 0, stream>>>(pbest, pbi, maxind);
    finalize<<<16, 256, 0, stream>>>(da, prune_cols, maxind, out_imp, out_simi);
}

// Round 7
// 1438.871 us; speedup vs baseline: 1.7299x; 1.0976x over previous
//
#include <hip/hip_runtime.h>
#include <math.h>

#define NT 4096
#define DM 1152
#define NH 16
#define DH 72
#define KRET 1638
#define NPR (NT - KRET)
#define CSB 8
#define CHUNK 205
#define SCALE 0.11785113019775793f
#define RSPLIT 2048.0f
#define INV_RSPLIT 4.8828125e-4f

typedef __attribute__((ext_vector_type(8))) short bf16x8;
typedef _Float16 f16;
typedef __attribute__((ext_vector_type(8))) _Float16 f16x8;
typedef __attribute__((ext_vector_type(4))) float f32x4;
typedef unsigned short ushort_t;

#define MFMA16(a, b, c) __builtin_amdgcn_mfma_f32_16x16x32_f16(a, b, c, 0, 0, 0)
#define MFMABF(a, b, c) __builtin_amdgcn_mfma_f32_16x16x32_bf16(a, b, c, 0, 0, 0)

__device__ inline ushort_t f2b(float f) {
    union { float f; unsigned int u; } v; v.f = f;
    unsigned int u = v.u;
    return (ushort_t)((u + 0x7FFFu + ((u >> 16) & 1u)) >> 16);
}

__device__ inline float b2f(ushort_t u) {
    union { unsigned int u; float f; } v; v.u = ((unsigned int)u) << 16;
    return v.f;
}

// tiled Q/K address: [NH][rowblk 256][ks 3][r 16][ki 32]
__device__ inline size_t qkAddr(int h, int row, int ks, int ki) {
    return ((((size_t)h * 256 + (row >> 4)) * 3 + ks) * 16 + (row & 15)) * 32 + ki;
}

// ---------- split x into fp16 hi/lo(x2048) planes + bf16 copy ----------------
__global__ __launch_bounds__(256) void split_x(
    const float* __restrict__ in, f16* __restrict__ x0, f16* __restrict__ x1,
    ushort_t* __restrict__ xb, int nElem)
{
    int i = blockIdx.x * 256 + threadIdx.x;
    int stride = gridDim.x * 256;
    for (; i < nElem; i += stride) {
        float v = in[i];
        f16 h0 = (f16)v;
        float res = (v - (float)h0) * RSPLIT;
        x0[i] = h0;
        x1[i] = (f16)res;
        xb[i] = f2b(v);
    }
}

__global__ __launch_bounds__(256) void transposeW_split(
    const float* __restrict__ W, f16* __restrict__ T0, f16* __restrict__ T1, int n)
{
    __shared__ float t[32][33];
    int bx = blockIdx.x * 32, by = blockIdx.y * 32;
    int tx = threadIdx.x & 31, ty = threadIdx.x >> 5;
    for (int i = ty; i < 32; i += 8)
        t[i][tx] = W[(size_t)(by + i) * n + bx + tx];
    __syncthreads();
    for (int i = ty; i < 32; i += 8) {
        float v = t[tx][i];
        f16 h0 = (f16)v;
        float res = (v - (float)h0) * RSPLIT;
        T0[(size_t)(bx + i) * n + by + tx] = h0;
        T1[(size_t)(bx + i) * n + by + tx] = (f16)res;
    }
}

__global__ __launch_bounds__(256) void transposeW_bf16(
    const float* __restrict__ W, ushort_t* __restrict__ WT, int n)
{
    __shared__ ushort_t t[32][33];
    int bx = blockIdx.x * 32, by = blockIdx.y * 32;
    int tx = threadIdx.x & 31, ty = threadIdx.x >> 5;
    for (int i = ty; i < 32; i += 8)
        t[i][tx] = f2b(W[(size_t)(by + i) * n + bx + tx]);
    __syncthreads();
    for (int i = ty; i < 32; i += 8)
        WT[(size_t)(bx + i) * n + by + tx] = t[tx][i];
}

// ---------- LDS-tiled split projection -> MFMA-tiled per-head output ---------
__global__ __launch_bounds__(256) void proj_split3(
    const f16* __restrict__ A0, const f16* __restrict__ A1,
    const f16* __restrict__ B0, const f16* __restrict__ B1,
    f16* __restrict__ Qt0, f16* __restrict__ Qt1)
{
    __shared__ __align__(16) f16 As0[128][40];
    __shared__ __align__(16) f16 As1[128][40];
    __shared__ __align__(16) f16 Bs0[64][40];
    __shared__ __align__(16) f16 Bs1[64][40];
    const int tid = threadIdx.x;
    const int wave = tid >> 6, lane = tid & 63;
    const int r = lane & 15, g = lane >> 4;
    const int row0 = blockIdx.y * 128;
    const int col0 = blockIdx.x * 64;
    f32x4 accM[2][4] = {}, accC[2][4] = {};
    for (int k0 = 0; k0 < DM; k0 += 32) {
        for (int idx = tid; idx < 128 * 4; idx += 256) {
            int row = idx >> 2, c = idx & 3;
            size_t src = (size_t)(row0 + row) * DM + k0 + c * 8;
            *(f16x8*)&As0[row][c * 8] = *(const f16x8*)(A0 + src);
            *(f16x8*)&As1[row][c * 8] = *(const f16x8*)(A1 + src);
        }
        for (int idx = tid; idx < 64 * 4; idx += 256) {
            int row = idx >> 2, c = idx & 3;
            size_t src = (size_t)(col0 + row) * DM + k0 + c * 8;
            *(f16x8*)&Bs0[row][c * 8] = *(const f16x8*)(B0 + src);
            *(f16x8*)&Bs1[row][c * 8] = *(const f16x8*)(B1 + src);
        }
        __syncthreads();
        f16x8 a0[2], a1[2], b0[4], b1[4];
#pragma unroll
        for (int rf = 0; rf < 2; ++rf) {
            a0[rf] = *(const f16x8*)&As0[wave * 32 + rf * 16 + r][g * 8];
            a1[rf] = *(const f16x8*)&As1[wave * 32 + rf * 16 + r][g * 8];
        }
#pragma unroll
        for (int cf = 0; cf < 4; ++cf) {
            b0[cf] = *(const f16x8*)&Bs0[cf * 16 + r][g * 8];
            b1[cf] = *(const f16x8*)&Bs1[cf * 16 + r][g * 8];
        }
#pragma unroll
        for (int rf = 0; rf < 2; ++rf)
#pragma unroll
            for (int cf = 0; cf < 4; ++cf) {
                accM[rf][cf] = MFMA16(a0[rf], b0[cf], accM[rf][cf]);
                accC[rf][cf] = MFMA16(a0[rf], b1[cf], accC[rf][cf]);
                accC[rf][cf] = MFMA16(a1[rf], b0[cf], accC[rf][cf]);
            }
        __syncthreads();
    }
#pragma unroll
    for (int rf = 0; rf < 2; ++rf)
#pragma unroll
        for (int cf = 0; cf < 4; ++cf) {
            int col = col0 + cf * 16 + r;
            int head = col / DH;
            int c = col - head * DH;
            int ks = c >> 5, ki = c & 31;
#pragma unroll
            for (int j = 0; j < 4; ++j) {
                int row = row0 + wave * 32 + rf * 16 + g * 4 + j;
                float v = accM[rf][cf][j] + accC[rf][cf][j] * INV_RSPLIT;
                f16 h0 = (f16)v;
                float res = (v - (float)h0) * RSPLIT;
                size_t addr = qkAddr(head, row, ks, ki);
                Qt0[addr] = h0;
                Qt1[addr] = (f16)res;
            }
        }
}

// ---------- LDS-tiled bf16 MFMA GEMM; mode 0 = fp32 flat, 2 = Vp tiled -------
__global__ __launch_bounds__(256) void gemm_bf16_lds(
    const ushort_t* __restrict__ A, const ushort_t* __restrict__ BT,
    const float* __restrict__ bias, void* __restrict__ C, int mode,
    int Nn, int K)
{
    __shared__ __align__(16) ushort_t As[128][40];
    __shared__ __align__(16) ushort_t Bs[64][40];
    const int tid = threadIdx.x;
    const int wave = tid >> 6, lane = tid & 63;
    const int r = lane & 15, g = lane >> 4;
    const int row0 = blockIdx.y * 128;
    const int col0 = blockIdx.x * 64;
    f32x4 acc[2][4] = {};
    for (int k0 = 0; k0 < K; k0 += 32) {
        for (int idx = tid; idx < 128 * 4; idx += 256) {
            int row = idx >> 2, c = idx & 3;
            *(bf16x8*)&As[row][c * 8] = *(const bf16x8*)(A + (size_t)(row0 + row) * K + k0 + c * 8);
        }
        for (int idx = tid; idx < 64 * 4; idx += 256) {
            int row = idx >> 2, c = idx & 3;
            *(bf16x8*)&Bs[row][c * 8] = *(const bf16x8*)(BT + (size_t)(col0 + row) * K + k0 + c * 8);
        }
        __syncthreads();
        bf16x8 a[2], b[4];
#pragma unroll
        for (int rf = 0; rf < 2; ++rf)
            a[rf] = *(const bf16x8*)&As[wave * 32 + rf * 16 + r][g * 8];
#pragma unroll
        for (int cf = 0; cf < 4; ++cf)
            b[cf] = *(const bf16x8*)&Bs[cf * 16 + r][g * 8];
#pragma unroll
        for (int rf = 0; rf < 2; ++rf)
#pragma unroll
            for (int cf = 0; cf < 4; ++cf)
                acc[rf][cf] = MFMABF(a[rf], b[cf], acc[rf][cf]);
        __syncthreads();
    }
#pragma unroll
    for (int rf = 0; rf < 2; ++rf)
#pragma unroll
        for (int cf = 0; cf < 4; ++cf) {
            int col = col0 + cf * 16 + r;
            float bv = bias ? bias[col] : 0.f;
#pragma unroll
            for (int j = 0; j < 4; ++j) {
                int row = row0 + wave * 32 + rf * 16 + g * 4 + j;
                float vv = acc[rf][cf][j] + bv;
                if (mode == 2) {
                    int head = col / DH;
                    int d = col - head * DH;
                    size_t addr = (((size_t)head * 128 + (row >> 5)) * 80 + d) * 32 + (row & 31);
                    ((ushort_t*)C)[addr] = f2b(vv);
                } else {
                    ((float*)C)[(size_t)row * Nn + col] = vv;
                }
            }
        }
}

// ---------- pass A: per-row 1/rowsum of exp(S); K staged in LDS --------------
// grid (NT/64, NH), 256 threads (4 waves). Math bit-identical to rowsum3.
__global__ __launch_bounds__(256) void rowsum4(
    const f16* __restrict__ Qt0, const f16* __restrict__ Qt1,
    const f16* __restrict__ Kt0, const f16* __restrict__ Kt1,
    float* __restrict__ invs)
{
    __shared__ __align__(16) f16 KL[2][6144];   // [plane][cf*3ks tiles of 512]
    const int tid = threadIdx.x;
    const int wv = tid >> 6, lane = tid & 63;
    const int r = lane & 15, g = lane >> 4;
    const int h = blockIdx.y;
    const int rowblk = blockIdx.x * 4 + wv;
    f16x8 a0[3], a1[3];
#pragma unroll
    for (int ks = 0; ks < 3; ++ks) {
        size_t o = ((((size_t)h * 256 + rowblk) * 3 + ks) * 16) * 32 + r * 32 + g * 8;
        a0[ks] = *(const f16x8*)(Qt0 + o);
        a1[ks] = *(const f16x8*)(Qt1 + o);
    }
    float rs0 = 0.f, rs1 = 0.f, rs2 = 0.f, rs3 = 0.f;
    for (int ct = 0; ct < 64; ++ct) {
        __syncthreads();
        const size_t ctBase = ((size_t)h * 256 + ct * 4) * 1536;
#pragma unroll
        for (int s = 0; s < 6; ++s) {
            int wc = s * 4 + wv;             // 0..23 wave-chunks of 1024B
            int plane = wc >= 12;
            int cip = wc - plane * 12;       // chunk within plane
            const f16* src = (plane ? Kt1 : Kt0) + ctBase + cip * 512 + lane * 8;
            *(f16x8*)&KL[plane][cip * 512 + lane * 8] = *(const f16x8*)src;
        }
        __syncthreads();
        f32x4 accM[4] = {}, accC[4] = {};
#pragma unroll
        for (int ks = 0; ks < 3; ++ks) {
#pragma unroll
            for (int cf = 0; cf < 4; ++cf) {
                f16x8 b0 = *(const f16x8*)&KL[0][(cf * 3 + ks) * 512 + r * 32 + g * 8];
                f16x8 b1 = *(const f16x8*)&KL[1][(cf * 3 + ks) * 512 + r * 32 + g * 8];
                accM[cf] = MFMA16(a0[ks], b0, accM[cf]);
                accC[cf] = MFMA16(a0[ks], b1, accC[cf]);
                accC[cf] = MFMA16(a1[ks], b0, accC[cf]);
            }
        }
#pragma unroll
        for (int cf = 0; cf < 4; ++cf) {
            rs0 += __expf((accM[cf][0] + accC[cf][0] * INV_RSPLIT) * SCALE);
            rs1 += __expf((accM[cf][1] + accC[cf][1] * INV_RSPLIT) * SCALE);
            rs2 += __expf((accM[cf][2] + accC[cf][2] * INV_RSPLIT) * SCALE);
            rs3 += __expf((accM[cf][3] + accC[cf][3] * INV_RSPLIT) * SCALE);
        }
    }
#pragma unroll
    for (int m = 1; m <= 8; m <<= 1) {
        rs0 += __shfl_xor(rs0, m);
        rs1 += __shfl_xor(rs1, m);
        rs2 += __shfl_xor(rs2, m);
        rs3 += __shfl_xor(rs3, m);
    }
    if (r == 0) {
        int rbase = rowblk * 16 + g * 4;
        invs[(size_t)h * NT + rbase + 0] = 1.0f / rs0;
        invs[(size_t)h * NT + rbase + 1] = 1.0f / rs1;
        invs[(size_t)h * NT + rbase + 2] = 1.0f / rs2;
        invs[(size_t)h * NT + rbase + 3] = 1.0f / rs3;
    }
}

// ---------- pass B: fused QK^T->P->attn(+pair)->PV; K staged in LDS ----------
__global__ __launch_bounds__(256) void fused4(
    const f16* __restrict__ Qt0, const f16* __restrict__ Qt1,
    const f16* __restrict__ Kt0, const f16* __restrict__ Kt1,
    const float* __restrict__ invs, const ushort_t* __restrict__ Vp,
    float* __restrict__ attn, ushort_t* __restrict__ part_pv,
    int hpair, int first)
{
    __shared__ __align__(16) f16 KL[4][6144];   // [hh*2+plane]
    __shared__ ushort_t Pt[64][88];
    const int tid = threadIdx.x;
    const int wr = tid >> 6, lane = tid & 63;
    const int r = lane & 15, g = lane >> 4;
    const int cs = blockIdx.x;
    const int rowblk = blockIdx.y * 4 + wr;
    const int row0 = rowblk * 16;
    f16x8 a0[2][3], a1[2][3];
    float vinv[2][4];
    f32x4 oacc[2][5] = {};
#pragma unroll
    for (int hh = 0; hh < 2; ++hh) {
        int h = hpair * 2 + hh;
#pragma unroll
        for (int ks = 0; ks < 3; ++ks) {
            size_t o = ((((size_t)h * 256 + rowblk) * 3 + ks) * 16) * 32 + r * 32 + g * 8;
            a0[hh][ks] = *(const f16x8*)(Qt0 + o);
            a1[hh][ks] = *(const f16x8*)(Qt1 + o);
        }
#pragma unroll
        for (int j = 0; j < 4; ++j)
            vinv[hh][j] = invs[(size_t)h * NT + row0 + g * 4 + j];
    }
    for (int ct = 0; ct < 8; ++ct) {
        const int colbase = cs * 512 + ct * 64;
        const int cb0 = colbase >> 4;           // colblk base
        __syncthreads();
#pragma unroll
        for (int s = 0; s < 12; ++s) {
            int wc = s * 4 + wr;                // 0..47 wave-chunks of 1024B
            int seg = wc / 12;                  // hh*2 + plane
            int cip = wc - seg * 12;
            int hh = seg >> 1, pl = seg & 1;
            const f16* base = pl ? Kt1 : Kt0;
            size_t srcOff = (((size_t)(hpair * 2 + hh) * 256 + cb0)) * 1536 + cip * 512 + lane * 8;
            *(f16x8*)&KL[seg][cip * 512 + lane * 8] = *(const f16x8*)(base + srcOff);
        }
        __syncthreads();
        float P0[4][4];
#pragma unroll
        for (int hh = 0; hh < 2; ++hh) {
            const int h = hpair * 2 + hh;
            f32x4 accM[4] = {}, accC[4] = {};
#pragma unroll
            for (int ks = 0; ks < 3; ++ks) {
#pragma unroll
                for (int cf = 0; cf < 4; ++cf) {
                    f16x8 b0 = *(const f16x8*)&KL[hh * 2 + 0][(cf * 3 + ks) * 512 + r * 32 + g * 8];
                    f16x8 b1 = *(const f16x8*)&KL[hh * 2 + 1][(cf * 3 + ks) * 512 + r * 32 + g * 8];
                    accM[cf] = MFMA16(a0[hh][ks], b0, accM[cf]);
                    accC[cf] = MFMA16(a0[hh][ks], b1, accC[cf]);
                    accC[cf] = MFMA16(a1[hh][ks], b0, accC[cf]);
                }
            }
#pragma unroll
            for (int cf = 0; cf < 4; ++cf) {
#pragma unroll
                for (int j = 0; j < 4; ++j) {
                    float s = (accM[cf][j] + accC[cf][j] * INV_RSPLIT) * SCALE;
                    float p = __expf(s) * vinv[hh][j];
                    Pt[wr * 16 + g * 4 + j][cf * 16 + r] = f2b(p);
                    if (hh == 0) {
                        P0[cf][j] = p;
                    } else {
                        int row = row0 + g * 4 + j;
                        size_t aoff = (size_t)row * NT + colbase + cf * 16 + r;
                        float av = (P0[cf][j] + p) * 0.0625f;
                        if (first) attn[aoff] = av;
                        else       attn[aoff] += av;
                    }
                }
            }
            const int kt0 = colbase >> 5;
#pragma unroll
            for (int ks2 = 0; ks2 < 2; ++ks2) {
                bf16x8 pa = *(const bf16x8*)&Pt[wr * 16 + r][ks2 * 32 + g * 8];
#pragma unroll
                for (int t = 0; t < 5; ++t) {
                    int col = t * 16 + r;
                    size_t vo = (((size_t)h * 128 + kt0 + ks2) * 80 + col) * 32 + g * 8;
                    bf16x8 b = *(const bf16x8*)(Vp + vo);
                    oacc[hh][t] = MFMABF(pa, b, oacc[hh][t]);
                }
            }
        }
    }
#pragma unroll
    for (int hh = 0; hh < 2; ++hh)
#pragma unroll
        for (int t = 0; t < 5; ++t) {
            int col = t * 16 + r;
            if (col < DH) {
#pragma unroll
                for (int j = 0; j < 4; ++j) {
                    int row = row0 + g * 4 + j;
                    part_pv[(((size_t)cs * 2 + hh) * NT + row) * DH + col] = f2b(oacc[hh][t][j]);
                }
            }
        }
}

__global__ __launch_bounds__(256) void pv_reduce2h(
    const ushort_t* __restrict__ part_pv, ushort_t* __restrict__ otmpb, int hpair)
{
    int idx = blockIdx.x * 256 + threadIdx.x;
    if (idx >= 2 * NT * DH) return;
    int hh = idx / (NT * DH);
    int rem = idx - hh * NT * DH;
    int row = rem / DH, col = rem - row * DH;
    float s = 0.f;
#pragma unroll
    for (int cs = 0; cs < CSB; ++cs)
        s += b2f(part_pv[(((size_t)cs * 2 + hh) * NT + row) * DH + col]);
    otmpb[(size_t)row * DM + (hpair * 2 + hh) * DH + col] = f2b(s);
}

// ---------- pagerank power iteration (fp32, unchanged) -----------------------
__global__ __launch_bounds__(256) void init_dist(float* __restrict__ d)
{
    int t = blockIdx.x * 256 + threadIdx.x;
    if (t < NT) d[t] = 1.0f / NT;
}

__global__ __launch_bounds__(256) void power_a(
    const float* __restrict__ attn, const float* __restrict__ din,
    float* __restrict__ part)
{
    int j = blockIdx.x * 256 + threadIdx.x;
    int i0 = blockIdx.y * 128;
    float acc = 0.f;
    for (int i = i0; i < i0 + 128; ++i)
        acc += din[i] * attn[(size_t)i * NT + j];
    part[(size_t)blockIdx.y * NT + j] = acc;
}

__global__ __launch_bounds__(256) void power_b(
    const float* __restrict__ part, float* __restrict__ dout)
{
    int j = blockIdx.x * 256 + threadIdx.x;
    float acc = 0.f;
    for (int ib = 0; ib < 32; ++ib) acc += part[(size_t)ib * NT + j];
    dout[j] = acc;
}

// ---------- top-k: tiled rank counting (deterministic int atomics) -----------
__global__ __launch_bounds__(256) void rank_count(
    const float* __restrict__ imp, int* __restrict__ rank, int* __restrict__ prank)
{
    __shared__ float sj[256];
    const int tid = threadIdx.x;
    const int jb = blockIdx.y * 256;
    sj[tid] = imp[jb + tid];
    __syncthreads();
    const int i = blockIdx.x * 256 + tid;
    const float mv = imp[i];
    int r = 0, rp = 0;
    for (int jj = 0; jj < 256; ++jj) {
        float vj = sj[jj];
        int j = jb + jj;
        int tie_low = (vj == mv) && (j < i);
        r  += (vj > mv) || tie_low;
        rp += (vj < mv) || tie_low;
    }
    atomicAdd(&rank[i], r);
    atomicAdd(&prank[i], rp);
}

__global__ __launch_bounds__(256) void scatter_topk2(
    const int* __restrict__ rank, const int* __restrict__ prank,
    float* __restrict__ out_imps, float* __restrict__ out_prune,
    int* __restrict__ imp_rows, int* __restrict__ prune_cols)
{
    __shared__ unsigned char fr[NT];
    __shared__ unsigned char fp[NT];
    __shared__ int sr[256], sp[256];
    const int tid = threadIdx.x;
    for (int t = tid; t < NT; t += 256) {
        fr[t] = rank[t] < KRET;
        fp[t] = prank[t] < NPR;
    }
    __syncthreads();
    const int base = tid * 16;
    int cr = 0, cp = 0;
#pragma unroll
    for (int e = 0; e < 16; ++e) { cr += fr[base + e]; cp += fp[base + e]; }
    sr[tid] = cr; sp[tid] = cp;
    __syncthreads();
    int pr = 0, pp = 0;
    for (int j = 0; j < tid; ++j) { pr += sr[j]; pp += sp[j]; }
#pragma unroll
    for (int e = 0; e < 16; ++e) {
        int i = base + e;
        if (fr[i]) { out_imps[pr] = (float)i; imp_rows[pr] = i; ++pr; }
        if (fp[i]) { out_prune[pp] = (float)i; prune_cols[pp] = i; ++pp; }
    }
}

__global__ __launch_bounds__(256) void argmax_part(
    const float* __restrict__ attn, const int* __restrict__ imp_rows,
    float* __restrict__ pbest, int* __restrict__ pbi)
{
    __shared__ int rows[CHUNK];
    const int tid = threadIdx.x;
    const int rc = blockIdx.y;
    const int r0 = rc * CHUNK;
    const int nr = min(KRET - r0, CHUNK);
    for (int t = tid; t < nr; t += 256) rows[t] = imp_rows[r0 + t];
    __syncthreads();
    const int j = blockIdx.x * 256 + tid;
    float best = -INFINITY;
    int bi = 0;
    for (int rr = 0; rr < nr; ++rr) {
        float val = attn[(size_t)rows[rr] * NT + j];
        if (val > best) { best = val; bi = r0 + rr; }
    }
    pbest[(size_t)rc * NT + j] = best;
    pbi[(size_t)rc * NT + j] = bi;
}

__global__ __launch_bounds__(256) void argmax_red(
    const float* __restrict__ pbest, const int* __restrict__ pbi,
    int* __restrict__ maxind)
{
    const int j = blockIdx.x * 256 + threadIdx.x;
    float best = -INFINITY;
    int bi = 0;
#pragma unroll
    for (int rc = 0; rc < 8; ++rc) {
        float val = pbest[(size_t)rc * NT + j];
        if (val > best) { best = val; bi = pbi[(size_t)rc * NT + j]; }
    }
    maxind[j] = bi;
}

__global__ __launch_bounds__(256) void finalize(
    const float* __restrict__ dist, const int* __restrict__ prune_cols,
    const int* __restrict__ maxind, float* __restrict__ out_imp,
    float* __restrict__ out_simi)
{
    int t = blockIdx.x * 256 + threadIdx.x;
    if (t < NT) out_imp[t] = dist[t];
    if (t < NPR) out_simi[t] = (float)maxind[prune_cols[t]];
}

extern "C" void kernel_launch(void* const* d_in, const int* in_sizes, int n_in,
                              void* d_out, int out_size, void* d_ws, size_t ws_size,
                              hipStream_t stream)
{
    const float* x  = (const float*)d_in[0];
    const float* Wq = (const float*)d_in[1];
    const float* Wk = (const float*)d_in[2];
    const float* Wv = (const float*)d_in[3];
    const float* Wo = (const float*)d_in[4];
    const float* bo = (const float*)d_in[5];
    float* out = (float*)d_out;

    const size_t QKT_EL = (size_t)NH * 256 * 3 * 16 * 32;   // 6.29M f16 per plane
    const size_t VP_EL  = (size_t)NH * 128 * 80 * 32;       // 5.24M bf16

    // ---- workspace layout (float units) ----
    float* ws = (float*)d_ws;
    size_t off = 0;
    float* attn = ws + off; off += (size_t)NT * NT;
    f16* Qt0 = (f16*)(ws + off); off += QKT_EL / 2;
    f16* Qt1 = (f16*)(ws + off); off += QKT_EL / 2;
    f16* Kt0 = (f16*)(ws + off); off += QKT_EL / 2;
    f16* Kt1 = (f16*)(ws + off); off += QKT_EL / 2;
    ushort_t* Vp = (ushort_t*)(ws + off); off += VP_EL / 2;
    size_t zero_floats = 4 * (QKT_EL / 2) + VP_EL / 2;      // Qt0..Vp contiguous
    ushort_t* otmpb = (ushort_t*)(ws + off); off += ((size_t)NT * DM) / 2;
    f16* X0 = (f16*)(ws + off); f16* X1 = X0 + (size_t)NT * DM; off += (size_t)NT * DM;
    f16* T0 = (f16*)(ws + off); f16* T1 = T0 + (size_t)DM * DM; off += (size_t)DM * DM;
    ushort_t* Wslot = (ushort_t*)(ws + off); off += ((size_t)DM * DM) / 2;
    float* invs    = ws + off; off += (size_t)NH * NT;
    ushort_t* part_pv = (ushort_t*)(ws + off); off += (size_t)CSB * 2 * NT * DH / 2;
    float* pbest   = ws + off; off += 8 * NT;
    int*   pbi     = (int*)(ws + off); off += 8 * NT;
    float* dist0 = ws + off; off += NT;
    float* dist1 = ws + off; off += NT;
    float* partial = ws + off; off += 32 * NT;
    int* rank      = (int*)(ws + off); off += NT;
    int* prank     = (int*)(ws + off); off += NT;
    int* imp_rows  = (int*)(ws + off); off += 2048;
    int* prune_cols= (int*)(ws + off); off += 2560;
    int* maxind    = (int*)(ws + off); off += NT;

    // setup-only alias inside attn region (dead before fused4 pair0 writes)
    ushort_t* xb = (ushort_t*)attn;

    // output layout
    float* out_out   = out;
    float* out_imp   = out + (size_t)NT * DM;
    float* out_imps  = out_imp + NT;
    float* out_prune = out_imps + KRET;
    float* out_simi  = out_prune + NPR;

    // ---- setup ----
    hipMemsetAsync(Qt0, 0, zero_floats * sizeof(float), stream);  // zero-pad tiles
    split_x<<<2048, 256, 0, stream>>>(x, X0, X1, xb, NT * DM);

    dim3 gT(DM / 32, DM / 32);
    dim3 gP(DM / 64, NT / 128);
    transposeW_split<<<gT, 256, 0, stream>>>(Wq, T0, T1, DM);
    proj_split3<<<gP, 256, 0, stream>>>(X0, X1, T0, T1, Qt0, Qt1);
    transposeW_split<<<gT, 256, 0, stream>>>(Wk, T0, T1, DM);
    proj_split3<<<gP, 256, 0, stream>>>(X0, X1, T0, T1, Kt0, Kt1);

    transposeW_bf16<<<gT, 256, 0, stream>>>(Wv, Wslot, DM);
    gemm_bf16_lds<<<gP, 256, 0, stream>>>(xb, Wslot, nullptr, Vp, 2, DM, DM);

    // ---- pass A: inverse row sums (LDS-staged K) ----
    rowsum4<<<dim3(NT / 64, NH), 256, 0, stream>>>(Qt0, Qt1, Kt0, Kt1, invs);

    // ---- pass B: fused attention, 2 heads per launch (LDS-staged K) ----
    for (int hp = 0; hp < NH / 2; ++hp) {
        fused4<<<dim3(CSB, NT / 64), 256, 0, stream>>>(
            Qt0, Qt1, Kt0, Kt1, invs, Vp, attn, part_pv, hp, hp == 0 ? 1 : 0);
        pv_reduce2h<<<(2 * NT * DH + 255) / 256, 256, 0, stream>>>(part_pv, otmpb, hp);
    }

    // ---- output projection ----
    transposeW_bf16<<<gT, 256, 0, stream>>>(Wo, Wslot, DM);
    gemm_bf16_lds<<<gP, 256, 0, stream>>>(otmpb, Wslot, bo, out_out, 0, DM, DM);

    // ---- pagerank ----
    init_dist<<<16, 256, 0, stream>>>(dist0);
    float* da = dist0;
    float* db = dist1;
    for (int it = 0; it < 5; ++it) {
        power_a<<<dim3(16, 32), 256, 0, stream>>>(attn, da, partial);
        power_b<<<16, 256, 0, stream>>>(partial, db);
        float* t = da; da = db; db = t;
    }

    // ---- top-k ----
    hipMemsetAsync(rank, 0, 2 * NT * sizeof(int), stream);
    rank_count<<<dim3(16, 16), 256, 0, stream>>>(da, rank, prank);
    scatter_topk2<<<1, 256, 0, stream>>>(rank, prank, out_imps, out_prune,
                                         imp_rows, prune_cols);
    argmax_part<<<dim3(16, 8), 256, 0, stream>>>(attn, imp_rows, pbest, pbi);
    argmax_red<<<16, 256, 0, stream>>>(pbest, pbi, maxind);
    finalize<<<16, 256, 0, stream>>>(da, prune_cols, maxind, out_imp, out_simi);
}